// Round 18
// baseline (240.140 us; speedup 1.0000x reference)
//
#include <hip/hip_runtime.h>

typedef __attribute__((ext_vector_type(4))) float f32x4;
typedef __attribute__((ext_vector_type(8))) __bf16 bf16x8;

#define T_DIM 2048
#define B_DIM 4
#define C_DIM 1024
#define H_N 8
#define D_H 128
#define M_ROWS 8192   // B*T
#define MC ((size_t)M_ROWS * C_DIM)
#define LCH 64               // chunk length
#define NCH (T_DIM / LCH)    // 32 chunks
#define CHSZ (128 * 128)     // state tile elements
#define SWE(r) ((((r) ^ ((r) >> 3)) & 7) << 3)

#define GLDS16(g, l) __builtin_amdgcn_global_load_lds( \
    (const __attribute__((address_space(1))) void*)(g), \
    (__attribute__((address_space(3))) void*)(l), 16, 0, 0)

// ---------------- merged prep ----------------
__global__ __launch_bounds__(256) void prep_all_k(
    const float* __restrict__ x, __bf16* __restrict__ xb,
    const float* __restrict__ W0, const float* __restrict__ W1,
    const float* __restrict__ W2, const float* __restrict__ W3,
    __bf16* __restrict__ WT,
    float2* __restrict__ tab,
    const float* __restrict__ Wb, const float* __restrict__ Wm,
    __bf16* __restrict__ WbmT) {
    __shared__ float t[64][65];
    int bid = blockIdx.x;
    int tid = threadIdx.x;
    if (bid < 4096) {
        int i = bid * 256 + tid;
        f32x4 a = ((const f32x4*)x)[i * 2];
        f32x4 b = ((const f32x4*)x)[i * 2 + 1];
        bf16x8 o;
        o[0] = (__bf16)a.x; o[1] = (__bf16)a.y; o[2] = (__bf16)a.z; o[3] = (__bf16)a.w;
        o[4] = (__bf16)b.x; o[5] = (__bf16)b.y; o[6] = (__bf16)b.z; o[7] = (__bf16)b.w;
        ((bf16x8*)xb)[i] = o;
    } else if (bid < 5120) {
        int tt = bid - 4096;
        int wz = tt >> 8, rem = tt & 255;
        int r0 = (rem >> 4) * 64, c0 = (rem & 15) * 64;
        const float* W = wz == 0 ? W0 : wz == 1 ? W1 : wz == 2 ? W2 : W3;
        __bf16* o = WT + (size_t)wz * C_DIM * C_DIM;
        #pragma unroll
        for (int it = 0; it < 4; ++it) {
            int idx = it * 256 + tid;
            int r = idx >> 4, c4 = (idx & 15) * 4;
            f32x4 v = *(const f32x4*)(W + (size_t)(r0 + r) * C_DIM + c0 + c4);
            t[r][c4] = v.x; t[r][c4 + 1] = v.y; t[r][c4 + 2] = v.z; t[r][c4 + 3] = v.w;
        }
        __syncthreads();
        #pragma unroll
        for (int it = 0; it < 2; ++it) {
            int idx = it * 256 + tid;
            int n = idx >> 3, k8 = (idx & 7) * 8;
            bf16x8 ov;
            #pragma unroll
            for (int j = 0; j < 8; ++j) ov[j] = (__bf16)t[k8 + j][n];
            *(bf16x8*)(o + (size_t)(c0 + n) * C_DIM + r0 + k8) = ov;
        }
    } else {
        int sp = bid - 5120;
        if (sp < 512) {
            int idx = sp * 256 + tid;
            int tq = idx >> 6, i = idx & 63;
            float freq = expf(-(2.0f * (float)i / 128.0f) * 9.210340371976184f);
            float a = (float)tq * freq;
            tab[idx] = make_float2(cosf(a), sinf(a));
        } else {
            int n = sp - 512;               // 0..31
            int col = n & 15;
            const float* W = (n < 16) ? Wb : Wm;
            for (int k = tid; k < C_DIM; k += 256)
                WbmT[(size_t)n * C_DIM + k] = (__bf16)W[(size_t)k * 16 + col];
        }
    }
}

// ---------------- beta/mix via MFMA ----------------
__global__ __launch_bounds__(256) void betamix_mfma(
    const __bf16* __restrict__ xb, const __bf16* __restrict__ WbmT,
    const float* __restrict__ bb, const float* __restrict__ bm,
    float* __restrict__ beta, float* __restrict__ mix) {
    __shared__ __bf16 As[2][32 * 64];   // 2 x 4 KB

    int tid = threadIdx.x;
    int w = tid >> 6, lane = tid & 63;
    int lr = lane & 15, lg = lane >> 4;
    int ifr = w >> 1, j = w & 1;
    int rows0 = blockIdx.x * 32;

    int srow = tid >> 3;
    int sg = (tid & 7) ^ (srow & 7);
    size_t aoff = (size_t)(rows0 + srow) * C_DIM + sg * 8;
    int ldso = w * 64 * 16;

    f32x4 acc = {};
    const __bf16* Wrow = WbmT + (size_t)(j * 16 + lr) * C_DIM;

    GLDS16(xb + aoff, (char*)As[0] + ldso);
    asm volatile("s_waitcnt vmcnt(0)" ::: "memory");
    __syncthreads();

    for (int t = 0; t < 16; ++t) {
        int cur = t & 1;
        if (t < 15) GLDS16(xb + aoff + (t + 1) * 64, (char*)As[cur ^ 1] + ldso);
        #pragma unroll
        for (int ss = 0; ss < 2; ++ss) {
            int ar = ifr * 16 + lr;
            bf16x8 af = *(const bf16x8*)((char*)As[cur] + ar * 128 + (((ss * 4 + lg) ^ (ar & 7)) << 4));
            bf16x8 bf = *(const bf16x8*)(Wrow + t * 64 + ss * 32 + lg * 8);
            acc = __builtin_amdgcn_mfma_f32_16x16x32_bf16(af, bf, acc, 0, 0, 0);
        }
        asm volatile("s_waitcnt vmcnt(0)" ::: "memory");
        __syncthreads();
    }

    float bias = (j ? bm : bb)[lr];
    #pragma unroll
    for (int r = 0; r < 4; ++r) {
        int row = rows0 + ifr * 16 + lg * 4 + r;
        float v = acc[r] + bias;
        if (j == 0) {
            beta[(size_t)row * 16 + lr] = 1.f / (1.f + expf(-v));
        } else {
            float other = __shfl_xor(v, 1);
            float mx = fmaxf(v, other);
            float e = expf(v - mx), eo = expf(other - mx);
            mix[(size_t)row * 16 + lr] = e / (e + eo);
        }
    }
}

// ---------------- decay precompute ----------------
__global__ __launch_bounds__(256) void decay_k(
    const float* __restrict__ beta, const float* __restrict__ mixp,
    const int* __restrict__ mask,
    float* __restrict__ wvm, float* __restrict__ rcm,
    float* __restrict__ qsc, float* __restrict__ cumLg) {
    int gw = blockIdx.x * 4 + (threadIdx.x >> 6);
    int s = threadIdx.x & 63;
    int scan = gw >> 5, c = gw & 31;
    int b = scan >> 4, hh = scan & 15;
    size_t row = (size_t)b * T_DIM + c * LCH + s;
    int mk = mask[row];
    float mf = mk ? 1.f : 0.f;
    float bt = mk ? beta[row * 16 + hh] : 1.f;
    float mx = mk ? mixp[row * 16 + hh] : 0.f;
    float cum = bt;
    #pragma unroll
    for (int off = 1; off < 64; off <<= 1) {
        float p = __shfl(cum, (s >= off) ? s - off : 0);
        if (s >= off) cum *= p;
    }
    float cl = __shfl(cum, 63);
    size_t o = (size_t)scan * T_DIM + c * LCH + s;
    wvm[o] = mf * cl / cum;
    rcm[o] = mf / cum;
    qsc[o] = mf * mx * cum;
    if (s == 63) cumLg[scan * NCH + c] = cl;
}

// ---------------- fused q|k|v GEMM: 256x256 deep tile, 8 waves -------------
// 512 thr = 8 waves (2M x 4N), per-wave 128x64 out (acc[8][4]). BK=64.
// LDS 128 KB = 2 dbuf x (A 32K + B 32K). Per K-tile: issue next tile's 8
// global_load_lds FIRST, then 24 swizzled ds_read_b128 + 64 MFMA on current
// buffer, then ONE __syncthreads (drains prefetch + fences buffer hand-off).
__global__ __launch_bounds__(512, 2) void gemm_qkv256(
    const __bf16* __restrict__ A, const __bf16* __restrict__ BT,
    __bf16* __restrict__ outq, const float2* __restrict__ rope_tab) {
    __shared__ __bf16 As[2][256 * 64];   // 2 x 32 KB
    __shared__ __bf16 Bs[2][256 * 64];   // 2 x 32 KB
    const int K = C_DIM;

    int tid = threadIdx.x;
    // 384 tiles = 32 bm x 12 bn ; XCD round-robin
    int bid = ((int)blockIdx.x & 7) * 48 + ((int)blockIdx.x >> 3);
    int bm = bid / 12, bn = bid % 12;
    int m_base = bm << 8, n_base = bn << 8;
    int w = tid >> 6, lane = tid & 63;
    int lr = lane & 15, lg = lane >> 4;
    int wr = w >> 2, wc = w & 3;                 // wave grid 2M x 4N
    int wm = wr * 128, wn = wc * 64;             // wave output origin

    // staging: 2048 granules of 16B per matrix per K-tile = 4 issues/thread
    size_t aoff[4], boff[4];
    int ldso[4];
    #pragma unroll
    for (int it = 0; it < 4; ++it) {
        int gi = it * 512 + tid;
        int row = gi >> 3;
        int gr = (gi & 7) ^ (row & 7);           // pre-swizzled source granule
        aoff[it] = (size_t)(m_base + row) * K + gr * 8;
        boff[it] = (size_t)(n_base + row) * K + gr * 8;
        ldso[it] = (it * 512 + w * 64) * 16;     // linear LDS dest, wave-uniform base
    }

#define STAGE_Q(bufi, k0)                                                   \
    _Pragma("unroll")                                                       \
    for (int it = 0; it < 4; ++it) {                                        \
        GLDS16(A + aoff[it] + (k0), (char*)As[bufi] + ldso[it]);            \
        GLDS16(BT + boff[it] + (k0), (char*)Bs[bufi] + ldso[it]);           \
    }

    f32x4 acc[8][4] = {};

    STAGE_Q(0, 0);
    __syncthreads();                             // tile 0 resident

    const int nt = K >> 6;                       // 16 K-tiles
    for (int t = 0; t < nt; ++t) {
        int cur = t & 1;
        if (t + 1 < nt) STAGE_Q(cur ^ 1, (t + 1) * 64);   // issue early
        #pragma unroll
        for (int s = 0; s < 2; ++s) {            // two k=32 slices
            bf16x8 bfr[4], af[8];
            #pragma unroll
            for (int j = 0; j < 4; ++j) {
                int br = wn + j * 16 + lr;
                bfr[j] = *(const bf16x8*)((char*)Bs[cur] + br * 128 + (((s * 4 + lg) ^ (br & 7)) << 4));
            }
            #pragma unroll
            for (int i = 0; i < 8; ++i) {
                int ar = wm + i * 16 + lr;
                af[i] = *(const bf16x8*)((char*)As[cur] + ar * 128 + (((s * 4 + lg) ^ (ar & 7)) << 4));
            }
            __builtin_amdgcn_s_setprio(1);
            #pragma unroll
            for (int i = 0; i < 8; ++i)
                #pragma unroll
                for (int j = 0; j < 4; ++j)
                    acc[i][j] = __builtin_amdgcn_mfma_f32_16x16x32_bf16(af[i], bfr[j], acc[i][j], 0, 0, 0);
            __builtin_amdgcn_s_setprio(0);
        }
        __syncthreads();   // drains prefetch (vmcnt 0) + fences buf[cur] reads
    }
#undef STAGE_Q

    #pragma unroll
    for (int i = 0; i < 8; ++i) {
        #pragma unroll
        for (int j = 0; j < 4; ++j) {
            #pragma unroll
            for (int r = 0; r < 4; ++r) {
                int grow = m_base + wm + i * 16 + (lg << 2) + r;
                int gcol = n_base + wn + j * 16 + lr;
                float val = acc[i][j][r];
                int buf = gcol >> 10;            // uniform per block (bn<4/8/12)
                int col = gcol & 1023;
                if (buf < 2) {
                    float partner = __shfl_xor(val, 1);
                    int t = grow & (T_DIM - 1);
                    int ii = (col & 127) >> 1;
                    float2 cs = rope_tab[t * 64 + ii];
                    val = (col & 1) ? (partner * cs.y + val * cs.x)
                                    : (val * cs.x - partner * cs.y);
                }
                outq[(size_t)buf * MC + (size_t)grow * C_DIM + col] = (__bf16)val;
            }
        }
    }
}

// ---------------- out GEMM: 64x128 tile, single-buffer, 1024 blocks --------
__global__ __launch_bounds__(256) void gemm_out64(
    const __bf16* __restrict__ A, const __bf16* __restrict__ BT,
    float* __restrict__ Cp, const float* __restrict__ bias) {
    __shared__ __bf16 As[64 * 64];    // 8 KB
    __shared__ __bf16 Bs[128 * 64];   // 16 KB
    const int K = C_DIM, N = C_DIM;

    int tid = threadIdx.x;
    int bid = ((int)blockIdx.x & 7) * 128 + ((int)blockIdx.x >> 3);
    int bm = bid >> 3, bn = bid & 7;
    int m_base = bm << 6, n_base = bn << 7;
    int w = tid >> 6, lane = tid & 63;
    int lr = lane & 15, lg = lane >> 4;
    int wm = (w >> 1) * 32, wn = (w & 1) * 64;

    size_t aoff[2], boff[4];
    int ldsoA[2], ldsoB[4];
    #pragma unroll
    for (int it = 0; it < 2; ++it) {
        int gi = it * 256 + tid;
        int row = gi >> 3;
        int g = (gi & 7) ^ (row & 7);
        aoff[it] = (size_t)(m_base + row) * K + g * 8;
        ldsoA[it] = (it * 256 + w * 64) * 16;
    }
    #pragma unroll
    for (int it = 0; it < 4; ++it) {
        int gi = it * 256 + tid;
        int row = gi >> 3;
        int g = (gi & 7) ^ (row & 7);
        boff[it] = (size_t)(n_base + row) * K + g * 8;
        ldsoB[it] = (it * 256 + w * 64) * 16;
    }

    f32x4 acc[2][4] = {};

    for (int k0 = 0; k0 < K; k0 += 64) {
        __syncthreads();
        #pragma unroll
        for (int it = 0; it < 2; ++it)
            GLDS16(A + aoff[it] + k0, (char*)As + ldsoA[it]);
        #pragma unroll
        for (int it = 0; it < 4; ++it)
            GLDS16(BT + boff[it] + k0, (char*)Bs + ldsoB[it]);
        __syncthreads();
        #pragma unroll
        for (int ss = 0; ss < 2; ++ss) {
            bf16x8 af[2], bfr[4];
            #pragma unroll
            for (int i = 0; i < 2; ++i) {
                int ar = wm + i * 16 + lr;
                af[i] = *(const bf16x8*)((char*)As + ar * 128 + (((ss * 4 + lg) ^ (ar & 7)) << 4));
            }
            #pragma unroll
            for (int j = 0; j < 4; ++j) {
                int br = wn + j * 16 + lr;
                bfr[j] = *(const bf16x8*)((char*)Bs + br * 128 + (((ss * 4 + lg) ^ (br & 7)) << 4));
            }
            #pragma unroll
            for (int i = 0; i < 2; ++i)
                #pragma unroll
                for (int j = 0; j < 4; ++j)
                    acc[i][j] = __builtin_amdgcn_mfma_f32_16x16x32_bf16(af[i], bfr[j], acc[i][j], 0, 0, 0);
        }
    }

    #pragma unroll
    for (int i = 0; i < 2; ++i) {
        #pragma unroll
        for (int j = 0; j < 4; ++j) {
            #pragma unroll
            for (int r = 0; r < 4; ++r) {
                int grow = m_base + wm + i * 16 + (lg << 2) + r;
                int gcol = n_base + wn + j * 16 + lr;
                Cp[(size_t)grow * N + gcol] = acc[i][j][r] + bias[gcol];
            }
        }
    }
}

// ============ chunk-parallel scan ============
__global__ __launch_bounds__(256) void chunk_sum_k(
    const __bf16* __restrict__ kg, const __bf16* __restrict__ vg,
    const float* __restrict__ wvm, __bf16* __restrict__ BT) {
    __shared__ __bf16 KT[128 * 64];
    __shared__ __bf16 VT[128 * 64];

    int tid = threadIdx.x;
    int c = blockIdx.x, kk = blockIdx.y, bh = blockIdx.z;
    int b = bh >> 3, h = bh & 7;
    int scan = bh * 2 + kk;
    size_t rowb = (size_t)b * T_DIM + c * LCH;
    size_t wb = (size_t)scan * T_DIM + c * LCH;

    #pragma unroll
    for (int it = 0; it < 4; ++it) {
        int f = tid + it * 256;
        int s = f >> 4, c8 = (f & 15) * 8;
        size_t g = (rowb + s) * C_DIM + h * D_H + c8;
        bf16x8 kv = *(const bf16x8*)(kg + g);
        bf16x8 vv = *(const bf16x8*)(vg + g);
        float ws_ = wvm[wb + s];
        #pragma unroll
        for (int j = 0; j < 8; ++j) {
            int d = c8 + j;
            KT[d * 64 + (s ^ SWE(d))] = (__bf16)(ws_ * (float)kv[j]);
            VT[d * 64 + (s ^ SWE(d))] = vv[j];
        }
    }
    __syncthreads();

    int w = tid >> 6, l = tid & 63;
    int lr = l & 15, lg = l >> 4;
    f32x4 acc[2][8] = {};
    #pragma unroll
    for (int kt = 0; kt < 2; ++kt) {
        int col = kt * 32 + lg * 8;
        bf16x8 aV[2], bK[8];
        #pragma unroll
        for (int et = 0; et < 2; ++et) {
            int e = w * 32 + et * 16 + lr;
            aV[et] = *(const bf16x8*)&VT[e * 64 + (col ^ SWE(e))];
        }
        #pragma unroll
        for (int dt = 0; dt < 8; ++dt) {
            int d = dt * 16 + lr;
            bK[dt] = *(const bf16x8*)&KT[d * 64 + (col ^ SWE(d))];
        }
        #pragma unroll
        for (int et = 0; et < 2; ++et)
            #pragma unroll
            for (int dt = 0; dt < 8; ++dt)
                acc[et][dt] = __builtin_amdgcn_mfma_f32_16x16x32_bf16(aV[et], bK[dt], acc[et][dt], 0, 0, 0);
    }

    __bf16* bout = BT + ((size_t)scan * NCH + c) * CHSZ;
    #pragma unroll
    for (int et = 0; et < 2; ++et)
        #pragma unroll
        for (int dt = 0; dt < 8; ++dt)
            #pragma unroll
            for (int r = 0; r < 4; ++r) {
                int e = w * 32 + et * 16 + lg * 4 + r;
                bout[e * 128 + dt * 16 + lr] = (__bf16)acc[et][dt][r];
            }
}

__global__ __launch_bounds__(256) void chunk_scan_k(
    __bf16* __restrict__ BT, const float* __restrict__ cumLg) {
    int bid = blockIdx.x;
    int scan = bid >> 3, part = bid & 7;
    int tid = threadIdx.x;
    int e = part * 16 + (tid >> 4);
    int d0 = (tid & 15) * 8;
    __bf16* base = BT + (size_t)scan * NCH * CHSZ + e * 128 + d0;
    const float* cl = cumLg + scan * NCH;
    float acc[8] = {};
    for (int c = 0; c < NCH; ++c) {
        bf16x8 bv = *(const bf16x8*)(base + (size_t)c * CHSZ);
        float g = cl[c];
        bf16x8 so;
        #pragma unroll
        for (int j = 0; j < 8; ++j) so[j] = (__bf16)acc[j];
        *(bf16x8*)(base + (size_t)c * CHSZ) = so;
        #pragma unroll
        for (int j = 0; j < 8; ++j) acc[j] = g * acc[j] + (float)bv[j];
    }
}

__global__ __launch_bounds__(256, 3) void chunk_out_k(
    const __bf16* __restrict__ qg, const __bf16* __restrict__ kg,
    const __bf16* __restrict__ vg, const __bf16* __restrict__ ST,
    const float* __restrict__ rcm, const float* __restrict__ qscg,
    __bf16* __restrict__ yg) {
    __shared__ __bf16 STs[2][64 * 128];  // 2 x 16 KB
    __shared__ __bf16 VT[64 * 64];       // 8 KB
    __shared__ __bf16 Ps[64 * 72];       // 9 KB
    __shared__ float rcumf[2][64], qscf[2][64];

    int tid = threadIdx.x;
    int c = blockIdx.x, eh = blockIdx.y, bh = blockIdx.z;
    int b = bh >> 3, h = bh & 7;
    int e0 = eh * 64;
    size_t rowb = (size_t)b * T_DIM + c * LCH;
    int w = tid >> 6, l = tid & 63;
    int lr = l & 15, lg = l >> 4;

    {
        const __bf16* stb = ST + ((size_t)(bh * 2) * NCH + c) * CHSZ + (size_t)e0 * 128;
        int r = tid >> 4, gran = tid & 15;
        size_t goff = (size_t)r * 128 + ((gran ^ (r & 7)) * 8);
        #pragma unroll
        for (int kk = 0; kk < 2; ++kk) {
            const __bf16* sp = stb + (size_t)kk * NCH * CHSZ;
            #pragma unroll
            for (int it = 0; it < 4; ++it) {
                GLDS16(sp + goff + (size_t)it * 16 * 128,
                       (char*)STs[kk] + (it * 256 + w * 64) * 16);
            }
        }
    }

    if (tid < 128) {
        int s = tid & 63, kk = tid >> 6;
        size_t o = (size_t)(bh * 2 + kk) * T_DIM + c * LCH + s;
        rcumf[kk][s] = rcm[o];
        qscf[kk][s] = qscg[o];
    }

    bf16x8 vreg[2];
    #pragma unroll
    for (int it = 0; it < 2; ++it) {
        int f = tid + it * 256;
        int s = f >> 3, c8 = (f & 7) * 8;
        vreg[it] = *(const bf16x8*)(vg + (rowb + s) * C_DIM + h * D_H + e0 + c8);
    }

    const __bf16* qrow = qg + (rowb + w * 16 + lr) * C_DIM + h * D_H;
    bf16x8 aQ[4];
    #pragma unroll
    for (int kt = 0; kt < 4; ++kt)
        aQ[kt] = *(const bf16x8*)(qrow + kt * 32 + lg * 8);

    const __bf16* kbase = kg + rowb * C_DIM + h * D_H;
    bf16x8 bkreg[16];
    #pragma unroll
    for (int st = 0; st < 4; ++st)
        #pragma unroll
        for (int kt = 0; kt < 4; ++kt)
            bkreg[st * 4 + kt] = *(const bf16x8*)(kbase + (size_t)(st * 16 + lr) * C_DIM + kt * 32 + lg * 8);

    #pragma unroll
    for (int it = 0; it < 2; ++it) {
        int f = tid + it * 256;
        int s = f >> 3, c8 = (f & 7) * 8;
        #pragma unroll
        for (int j = 0; j < 8; ++j) {
            int el = c8 + j;
            VT[el * 64 + (s ^ SWE(el))] = vreg[it][j];
        }
    }

    f32x4 Praw[4];
    #pragma unroll
    for (int st = 0; st < 4; ++st) {
        f32x4 p = {};
        #pragma unroll
        for (int kt = 0; kt < 4; ++kt)
            p = __builtin_amdgcn_mfma_f32_16x16x32_bf16(aQ[kt], bkreg[st * 4 + kt], p, 0, 0, 0);
        Praw[st] = p;
    }

    asm volatile("s_waitcnt vmcnt(0)" ::: "memory");
    __syncthreads();

    f32x4 yA[4] = {};
    #pragma unroll
    for (int kk = 0; kk < 2; ++kk) {
        #pragma unroll
        for (int st = 0; st < 4; ++st) {
            #pragma unroll
            for (int r = 0; r < 4; ++r) {
                int tl = w * 16 + lg * 4 + r;
                int sc = st * 16 + lr;
                float pv = (sc <= tl) ? Praw[st][r] * rcumf[kk][sc] * qscf[kk][tl] : 0.f;
                Ps[tl * 72 + sc] = (__bf16)pv;
            }
        }
        bf16x8 aP[2];
        #pragma unroll
        for (int k2 = 0; k2 < 2; ++k2)
            aP[k2] = *(const bf16x8*)&Ps[(w * 16 + lr) * 72 + k2 * 32 + lg * 8];

        __builtin_amdgcn_s_setprio(1);
        #pragma unroll
        for (int et = 0; et < 4; ++et) {
            int el = et * 16 + lr;
            f32x4 ys = {};
            #pragma unroll
            for (int kt = 0; kt < 4; ++kt) {
                bf16x8 bs = *(const bf16x8*)((char*)STs[kk] + el * 256 + (((kt * 4 + lg) ^ (el & 7)) << 4));
                ys = __builtin_amdgcn_mfma_f32_16x16x32_bf16(aQ[kt], bs, ys, 0, 0, 0);
            }
            f32x4 yp = {};
            #pragma unroll
            for (int k2 = 0; k2 < 2; ++k2) {
                bf16x8 bv = *(const bf16x8*)&VT[el * 64 + ((k2 * 32 + lg * 8) ^ SWE(el))];
                yp = __builtin_amdgcn_mfma_f32_16x16x32_bf16(aP[k2], bv, yp, 0, 0, 0);
            }
            #pragma unroll
            for (int r = 0; r < 4; ++r)
                yA[et][r] += ys[r] * qscf[kk][w * 16 + lg * 4 + r] + yp[r];
        }
        __builtin_amdgcn_s_setprio(0);
    }
    #pragma unroll
    for (int et = 0; et < 4; ++et)
        #pragma unroll
        for (int r = 0; r < 4; ++r) {
            size_t row = rowb + w * 16 + lg * 4 + r;
            yg[row * C_DIM + h * D_H + e0 + et * 16 + lr] = (__bf16)yA[et][r];
        }
}

extern "C" void kernel_launch(void* const* d_in, const int* in_sizes, int n_in,
                              void* d_out, int out_size, void* d_ws, size_t ws_size,
                              hipStream_t stream) {
    const float* x    = (const float*)d_in[0];
    const int*   mask = (const int*)d_in[1];
    const float* Wq   = (const float*)d_in[2];
    const float* Wk   = (const float*)d_in[3];
    const float* Wv   = (const float*)d_in[4];
    const float* Wb   = (const float*)d_in[5];
    const float* bb   = (const float*)d_in[6];
    const float* Wm   = (const float*)d_in[7];
    const float* bm   = (const float*)d_in[8];
    const float* Wo   = (const float*)d_in[9];
    const float* bo   = (const float*)d_in[10];
    float* out = (float*)d_out;

    __bf16* q    = (__bf16*)d_ws;                 // MC (q,k,v contiguous)
    __bf16* k    = q + MC;
    __bf16* v    = k + MC;
    __bf16* xb   = v + MC;                        // reused as ysum
    __bf16* WT   = xb + MC;                       // WqT|WkT|WvT|WoT
    __bf16* BT   = WT + (size_t)4 * C_DIM * C_DIM;
    float* beta  = (float*)(BT + (size_t)64 * NCH * CHSZ);
    float* mixb  = beta + M_ROWS * 16;
    float* cumL  = mixb + M_ROWS * 16;
    float* wvm   = cumL + 64 * NCH;
    float* rcm   = wvm + (size_t)64 * T_DIM;
    float* qscg  = rcm + (size_t)64 * T_DIM;
    float2* rope = (float2*)(qscg + (size_t)64 * T_DIM);
    __bf16* WbmT = (__bf16*)(rope + T_DIM * 64);
    __bf16* ysum = xb;

    prep_all_k<<<dim3(5664), dim3(256), 0, stream>>>(
        x, xb, Wq, Wk, Wv, Wo, WT, rope, Wb, Wm, WbmT);
    betamix_mfma<<<dim3(M_ROWS / 32), dim3(256), 0, stream>>>(xb, WbmT, bb, bm, beta, mixb);
    decay_k<<<dim3(512), dim3(256), 0, stream>>>(beta, mixb, mask, wvm, rcm, qscg, cumL);

    const size_t CC = (size_t)C_DIM * C_DIM;
    // fused q|k|v: 256x256 deep tile, 384 blocks x 512 threads
    gemm_qkv256<<<dim3(384), dim3(512), 0, stream>>>(xb, WT, q, rope);

    chunk_sum_k<<<dim3(NCH, 2, 32), dim3(256), 0, stream>>>(k, v, wvm, BT);
    chunk_scan_k<<<dim3(512), dim3(256), 0, stream>>>(BT, cumL);
    chunk_out_k<<<dim3(NCH, 2, 32), dim3(256), 0, stream>>>(q, k, v, BT, rcm, qscg, ysum);

    gemm_out64<<<dim3(1024), dim3(256), 0, stream>>>(ysum, WT + 3 * CC, out, bo);
}

// Round 19
// 215.806 us; speedup vs baseline: 1.1128x; 1.1128x over previous
//
#include <hip/hip_runtime.h>

typedef __attribute__((ext_vector_type(4))) float f32x4;
typedef __attribute__((ext_vector_type(8))) __bf16 bf16x8;

#define T_DIM 2048
#define B_DIM 4
#define C_DIM 1024
#define H_N 8
#define D_H 128
#define M_ROWS 8192   // B*T
#define MC ((size_t)M_ROWS * C_DIM)
#define LCH 64               // chunk length
#define NCH (T_DIM / LCH)    // 32 chunks
#define CHSZ (128 * 128)     // state tile elements
#define SWE(r) ((((r) ^ ((r) >> 3)) & 7) << 3)

#define GLDS16(g, l) __builtin_amdgcn_global_load_lds( \
    (const __attribute__((address_space(1))) void*)(g), \
    (__attribute__((address_space(3))) void*)(l), 16, 0, 0)

// ---------------- merged prep ----------------
__global__ __launch_bounds__(256) void prep_all_k(
    const float* __restrict__ x, __bf16* __restrict__ xb,
    const float* __restrict__ W0, const float* __restrict__ W1,
    const float* __restrict__ W2, const float* __restrict__ W3,
    __bf16* __restrict__ WT,
    float2* __restrict__ tab,
    const float* __restrict__ Wb, const float* __restrict__ Wm,
    __bf16* __restrict__ WbmT) {
    __shared__ float t[64][65];
    int bid = blockIdx.x;
    int tid = threadIdx.x;
    if (bid < 4096) {
        int i = bid * 256 + tid;
        f32x4 a = ((const f32x4*)x)[i * 2];
        f32x4 b = ((const f32x4*)x)[i * 2 + 1];
        bf16x8 o;
        o[0] = (__bf16)a.x; o[1] = (__bf16)a.y; o[2] = (__bf16)a.z; o[3] = (__bf16)a.w;
        o[4] = (__bf16)b.x; o[5] = (__bf16)b.y; o[6] = (__bf16)b.z; o[7] = (__bf16)b.w;
        ((bf16x8*)xb)[i] = o;
    } else if (bid < 5120) {
        int tt = bid - 4096;
        int wz = tt >> 8, rem = tt & 255;
        int r0 = (rem >> 4) * 64, c0 = (rem & 15) * 64;
        const float* W = wz == 0 ? W0 : wz == 1 ? W1 : wz == 2 ? W2 : W3;
        __bf16* o = WT + (size_t)wz * C_DIM * C_DIM;
        #pragma unroll
        for (int it = 0; it < 4; ++it) {
            int idx = it * 256 + tid;
            int r = idx >> 4, c4 = (idx & 15) * 4;
            f32x4 v = *(const f32x4*)(W + (size_t)(r0 + r) * C_DIM + c0 + c4);
            t[r][c4] = v.x; t[r][c4 + 1] = v.y; t[r][c4 + 2] = v.z; t[r][c4 + 3] = v.w;
        }
        __syncthreads();
        #pragma unroll
        for (int it = 0; it < 2; ++it) {
            int idx = it * 256 + tid;
            int n = idx >> 3, k8 = (idx & 7) * 8;
            bf16x8 ov;
            #pragma unroll
            for (int j = 0; j < 8; ++j) ov[j] = (__bf16)t[k8 + j][n];
            *(bf16x8*)(o + (size_t)(c0 + n) * C_DIM + r0 + k8) = ov;
        }
    } else {
        int sp = bid - 5120;
        if (sp < 512) {
            int idx = sp * 256 + tid;
            int tq = idx >> 6, i = idx & 63;
            float freq = expf(-(2.0f * (float)i / 128.0f) * 9.210340371976184f);
            float a = (float)tq * freq;
            tab[idx] = make_float2(cosf(a), sinf(a));
        } else {
            int n = sp - 512;               // 0..31
            int col = n & 15;
            const float* W = (n < 16) ? Wb : Wm;
            for (int k = tid; k < C_DIM; k += 256)
                WbmT[(size_t)n * C_DIM + k] = (__bf16)W[(size_t)k * 16 + col];
        }
    }
}

// ---------------- beta/mix via MFMA ----------------
__global__ __launch_bounds__(256) void betamix_mfma(
    const __bf16* __restrict__ xb, const __bf16* __restrict__ WbmT,
    const float* __restrict__ bb, const float* __restrict__ bm,
    float* __restrict__ beta, float* __restrict__ mix) {
    __shared__ __bf16 As[2][32 * 64];   // 2 x 4 KB

    int tid = threadIdx.x;
    int w = tid >> 6, lane = tid & 63;
    int lr = lane & 15, lg = lane >> 4;
    int ifr = w >> 1, j = w & 1;
    int rows0 = blockIdx.x * 32;

    int srow = tid >> 3;
    int sg = (tid & 7) ^ (srow & 7);
    size_t aoff = (size_t)(rows0 + srow) * C_DIM + sg * 8;
    int ldso = w * 64 * 16;

    f32x4 acc = {};
    const __bf16* Wrow = WbmT + (size_t)(j * 16 + lr) * C_DIM;

    GLDS16(xb + aoff, (char*)As[0] + ldso);
    asm volatile("s_waitcnt vmcnt(0)" ::: "memory");
    __syncthreads();

    for (int t = 0; t < 16; ++t) {
        int cur = t & 1;
        if (t < 15) GLDS16(xb + aoff + (t + 1) * 64, (char*)As[cur ^ 1] + ldso);
        #pragma unroll
        for (int ss = 0; ss < 2; ++ss) {
            int ar = ifr * 16 + lr;
            bf16x8 af = *(const bf16x8*)((char*)As[cur] + ar * 128 + (((ss * 4 + lg) ^ (ar & 7)) << 4));
            bf16x8 bf = *(const bf16x8*)(Wrow + t * 64 + ss * 32 + lg * 8);
            acc = __builtin_amdgcn_mfma_f32_16x16x32_bf16(af, bf, acc, 0, 0, 0);
        }
        asm volatile("s_waitcnt vmcnt(0)" ::: "memory");
        __syncthreads();
    }

    float bias = (j ? bm : bb)[lr];
    #pragma unroll
    for (int r = 0; r < 4; ++r) {
        int row = rows0 + ifr * 16 + lg * 4 + r;
        float v = acc[r] + bias;
        if (j == 0) {
            beta[(size_t)row * 16 + lr] = 1.f / (1.f + expf(-v));
        } else {
            float other = __shfl_xor(v, 1);
            float mx = fmaxf(v, other);
            float e = expf(v - mx), eo = expf(other - mx);
            mix[(size_t)row * 16 + lr] = e / (e + eo);
        }
    }
}

// ---------------- decay precompute ----------------
__global__ __launch_bounds__(256) void decay_k(
    const float* __restrict__ beta, const float* __restrict__ mixp,
    const int* __restrict__ mask,
    float* __restrict__ wvm, float* __restrict__ rcm,
    float* __restrict__ qsc, float* __restrict__ cumLg) {
    int gw = blockIdx.x * 4 + (threadIdx.x >> 6);
    int s = threadIdx.x & 63;
    int scan = gw >> 5, c = gw & 31;
    int b = scan >> 4, hh = scan & 15;
    size_t row = (size_t)b * T_DIM + c * LCH + s;
    int mk = mask[row];
    float mf = mk ? 1.f : 0.f;
    float bt = mk ? beta[row * 16 + hh] : 1.f;
    float mx = mk ? mixp[row * 16 + hh] : 0.f;
    float cum = bt;
    #pragma unroll
    for (int off = 1; off < 64; off <<= 1) {
        float p = __shfl(cum, (s >= off) ? s - off : 0);
        if (s >= off) cum *= p;
    }
    float cl = __shfl(cum, 63);
    size_t o = (size_t)scan * T_DIM + c * LCH + s;
    wvm[o] = mf * cl / cum;
    rcm[o] = mf / cum;
    qsc[o] = mf * mx * cum;
    if (s == 63) cumLg[scan * NCH + c] = cl;
}

// ---------------- fused q|k|v GEMM: single-buffered m97 structure --------
// r17 kernel, measured 98.7 us. grid 1536 = 8 XCDs x {8 bm x 3 bn-groups}.
__global__ __launch_bounds__(256) void gemm_qkv(
    const __bf16* __restrict__ A, const __bf16* __restrict__ BT,
    __bf16* __restrict__ outq, const float2* __restrict__ rope_tab) {
    __shared__ __bf16 As[128 * 64];
    __shared__ __bf16 Bs[128 * 64];
    const int K = C_DIM;

    int tid = threadIdx.x;
    int xcd = blockIdx.x & 7, lid = blockIdx.x >> 3;
    int g = lid >> 6, u = lid & 63;
    int bm = xcd * 8 + (u >> 3), bn = g * 8 + (u & 7);
    int m_base = bm << 7, n_base = bn << 7;
    int w = tid >> 6, lane = tid & 63;
    int lr = lane & 15, lg = lane >> 4;
    int wm = (w >> 1) * 64, wn = (w & 1) * 64;

    size_t aoff[4], boff[4];
    int ldso[4];
    #pragma unroll
    for (int it = 0; it < 4; ++it) {
        int gi = it * 256 + tid;
        int row = gi >> 3;
        int gr = (gi & 7) ^ (row & 7);
        aoff[it] = (size_t)(m_base + row) * K + gr * 8;
        boff[it] = (size_t)(n_base + row) * K + gr * 8;
        ldso[it] = (it * 256 + w * 64) * 16;
    }

    f32x4 acc[4][4] = {};

    for (int k0 = 0; k0 < K; k0 += 64) {
        __syncthreads();
        #pragma unroll
        for (int it = 0; it < 4; ++it) {
            GLDS16(A + aoff[it] + k0, (char*)As + ldso[it]);
            GLDS16(BT + boff[it] + k0, (char*)Bs + ldso[it]);
        }
        __syncthreads();
        #pragma unroll
        for (int ss = 0; ss < 2; ++ss) {
            bf16x8 af[4], bfr[4];
            #pragma unroll
            for (int i = 0; i < 4; ++i) {
                int ar = wm + i * 16 + lr;
                af[i] = *(const bf16x8*)((char*)As + ar * 128 + (((ss * 4 + lg) ^ (ar & 7)) << 4));
                int br = wn + i * 16 + lr;
                bfr[i] = *(const bf16x8*)((char*)Bs + br * 128 + (((ss * 4 + lg) ^ (br & 7)) << 4));
            }
            #pragma unroll
            for (int i = 0; i < 4; ++i)
                #pragma unroll
                for (int j = 0; j < 4; ++j)
                    acc[i][j] = __builtin_amdgcn_mfma_f32_16x16x32_bf16(af[i], bfr[j], acc[i][j], 0, 0, 0);
        }
    }

    #pragma unroll
    for (int i = 0; i < 4; ++i) {
        #pragma unroll
        for (int j = 0; j < 4; ++j) {
            #pragma unroll
            for (int r = 0; r < 4; ++r) {
                int grow = m_base + wm + i * 16 + (lg << 2) + r;
                int gcol = n_base + wn + j * 16 + lr;
                float val = acc[i][j][r];
                int buf = gcol >> 10;
                int col = gcol & 1023;
                if (buf < 2) {
                    float partner = __shfl_xor(val, 1);
                    int t = grow & (T_DIM - 1);
                    int ii = (col & 127) >> 1;
                    float2 cs = rope_tab[t * 64 + ii];
                    val = (col & 1) ? (partner * cs.y + val * cs.x)
                                    : (val * cs.x - partner * cs.y);
                }
                outq[(size_t)buf * MC + (size_t)grow * C_DIM + col] = (__bf16)val;
            }
        }
    }
}

// ---------------- out GEMM: 128x128 2-phase dbuf (r15 config) --------------
__global__ __launch_bounds__(256) void gemm_bt(
    const __bf16* __restrict__ A, const __bf16* __restrict__ BT,
    float* __restrict__ Cp, int M, int N, int K,
    const float* __restrict__ bias) {
    __shared__ __bf16 As[2][128 * 64];
    __shared__ __bf16 Bs[2][128 * 64];

    int tid = threadIdx.x;
    int nTN = N >> 7;
    int cpx = gridDim.x >> 3;
    int bid = ((int)blockIdx.x & 7) * cpx + ((int)blockIdx.x >> 3);
    int bm = bid / nTN, bn = bid % nTN;
    int m_base = bm << 7, n_base = bn << 7;
    int w = tid >> 6, lane = tid & 63;
    int lr = lane & 15, lg = lane >> 4;
    int wm = (w >> 1) * 64, wn = (w & 1) * 64;

    size_t aoff[4], boff[4];
    int ldso[4];
    #pragma unroll
    for (int it = 0; it < 4; ++it) {
        int gi = it * 256 + tid;
        int row = gi >> 3;
        int g = (gi & 7) ^ (row & 7);
        aoff[it] = (size_t)(m_base + row) * K + g * 8;
        boff[it] = (size_t)(n_base + row) * K + g * 8;
        ldso[it] = (it * 256 + w * 64) * 16;
    }

#define STAGE_G(bufi, k0)                                                   \
    _Pragma("unroll")                                                       \
    for (int it = 0; it < 4; ++it) {                                        \
        GLDS16(A + aoff[it] + (k0), (char*)As[bufi] + ldso[it]);            \
        GLDS16(BT + boff[it] + (k0), (char*)Bs[bufi] + ldso[it]);           \
    }

    f32x4 acc[4][4] = {};

    STAGE_G(0, 0);
    asm volatile("s_waitcnt vmcnt(0)" ::: "memory");
    __syncthreads();

    int nt = K >> 6;
    for (int t = 0; t < nt; ++t) {
        int cur = t & 1;
        if (t + 1 < nt) STAGE_G(cur ^ 1, (t + 1) * 64);
        #pragma unroll
        for (int ss = 0; ss < 2; ++ss) {
            bf16x8 af[4], bfr[4];
            #pragma unroll
            for (int i = 0; i < 4; ++i) {
                int ar = wm + i * 16 + lr;
                af[i] = *(const bf16x8*)((char*)As[cur] + ar * 128 + (((ss * 4 + lg) ^ (ar & 7)) << 4));
                int br = wn + i * 16 + lr;
                bfr[i] = *(const bf16x8*)((char*)Bs[cur] + br * 128 + (((ss * 4 + lg) ^ (br & 7)) << 4));
            }
            #pragma unroll
            for (int i = 0; i < 4; ++i)
                #pragma unroll
                for (int j = 0; j < 4; ++j)
                    acc[i][j] = __builtin_amdgcn_mfma_f32_16x16x32_bf16(af[i], bfr[j], acc[i][j], 0, 0, 0);
        }
        asm volatile("s_waitcnt vmcnt(0)" ::: "memory");
        __syncthreads();
    }
#undef STAGE_G

    #pragma unroll
    for (int i = 0; i < 4; ++i) {
        #pragma unroll
        for (int j = 0; j < 4; ++j) {
            #pragma unroll
            for (int r = 0; r < 4; ++r) {
                int grow = m_base + wm + i * 16 + (lg << 2) + r;
                int gcol = n_base + wn + j * 16 + lr;
                Cp[(size_t)grow * N + gcol] = acc[i][j][r] + bias[gcol];
            }
        }
    }
}

// ============ chunk-parallel scan ============
__global__ __launch_bounds__(256) void chunk_sum_k(
    const __bf16* __restrict__ kg, const __bf16* __restrict__ vg,
    const float* __restrict__ wvm, __bf16* __restrict__ BT) {
    __shared__ __bf16 KT[128 * 64];
    __shared__ __bf16 VT[128 * 64];

    int tid = threadIdx.x;
    int c = blockIdx.x, kk = blockIdx.y, bh = blockIdx.z;
    int b = bh >> 3, h = bh & 7;
    int scan = bh * 2 + kk;
    size_t rowb = (size_t)b * T_DIM + c * LCH;
    size_t wb = (size_t)scan * T_DIM + c * LCH;

    #pragma unroll
    for (int it = 0; it < 4; ++it) {
        int f = tid + it * 256;
        int s = f >> 4, c8 = (f & 15) * 8;
        size_t g = (rowb + s) * C_DIM + h * D_H + c8;
        bf16x8 kv = *(const bf16x8*)(kg + g);
        bf16x8 vv = *(const bf16x8*)(vg + g);
        float ws_ = wvm[wb + s];
        #pragma unroll
        for (int j = 0; j < 8; ++j) {
            int d = c8 + j;
            KT[d * 64 + (s ^ SWE(d))] = (__bf16)(ws_ * (float)kv[j]);
            VT[d * 64 + (s ^ SWE(d))] = vv[j];
        }
    }
    __syncthreads();

    int w = tid >> 6, l = tid & 63;
    int lr = l & 15, lg = l >> 4;
    f32x4 acc[2][8] = {};
    #pragma unroll
    for (int kt = 0; kt < 2; ++kt) {
        int col = kt * 32 + lg * 8;
        bf16x8 aV[2], bK[8];
        #pragma unroll
        for (int et = 0; et < 2; ++et) {
            int e = w * 32 + et * 16 + lr;
            aV[et] = *(const bf16x8*)&VT[e * 64 + (col ^ SWE(e))];
        }
        #pragma unroll
        for (int dt = 0; dt < 8; ++dt) {
            int d = dt * 16 + lr;
            bK[dt] = *(const bf16x8*)&KT[d * 64 + (col ^ SWE(d))];
        }
        #pragma unroll
        for (int et = 0; et < 2; ++et)
            #pragma unroll
            for (int dt = 0; dt < 8; ++dt)
                acc[et][dt] = __builtin_amdgcn_mfma_f32_16x16x32_bf16(aV[et], bK[dt], acc[et][dt], 0, 0, 0);
    }

    __bf16* bout = BT + ((size_t)scan * NCH + c) * CHSZ;
    #pragma unroll
    for (int et = 0; et < 2; ++et)
        #pragma unroll
        for (int dt = 0; dt < 8; ++dt)
            #pragma unroll
            for (int r = 0; r < 4; ++r) {
                int e = w * 32 + et * 16 + lg * 4 + r;
                bout[e * 128 + dt * 16 + lr] = (__bf16)acc[et][dt][r];
            }
}

__global__ __launch_bounds__(256) void chunk_scan_k(
    __bf16* __restrict__ BT, const float* __restrict__ cumLg) {
    int bid = blockIdx.x;
    int scan = bid >> 3, part = bid & 7;
    int tid = threadIdx.x;
    int e = part * 16 + (tid >> 4);
    int d0 = (tid & 15) * 8;
    __bf16* base = BT + (size_t)scan * NCH * CHSZ + e * 128 + d0;
    const float* cl = cumLg + scan * NCH;
    float acc[8] = {};
    for (int c = 0; c < NCH; ++c) {
        bf16x8 bv = *(const bf16x8*)(base + (size_t)c * CHSZ);
        float g = cl[c];
        bf16x8 so;
        #pragma unroll
        for (int j = 0; j < 8; ++j) so[j] = (__bf16)acc[j];
        *(bf16x8*)(base + (size_t)c * CHSZ) = so;
        #pragma unroll
        for (int j = 0; j < 8; ++j) acc[j] = g * acc[j] + (float)bv[j];
    }
}

__global__ __launch_bounds__(256, 3) void chunk_out_k(
    const __bf16* __restrict__ qg, const __bf16* __restrict__ kg,
    const __bf16* __restrict__ vg, const __bf16* __restrict__ ST,
    const float* __restrict__ rcm, const float* __restrict__ qscg,
    __bf16* __restrict__ yg) {
    __shared__ __bf16 STs[2][64 * 128];  // 2 x 16 KB
    __shared__ __bf16 VT[64 * 64];       // 8 KB
    __shared__ __bf16 Ps[64 * 72];       // 9 KB
    __shared__ float rcumf[2][64], qscf[2][64];

    int tid = threadIdx.x;
    int c = blockIdx.x, eh = blockIdx.y, bh = blockIdx.z;
    int b = bh >> 3, h = bh & 7;
    int e0 = eh * 64;
    size_t rowb = (size_t)b * T_DIM + c * LCH;
    int w = tid >> 6, l = tid & 63;
    int lr = l & 15, lg = l >> 4;

    {
        const __bf16* stb = ST + ((size_t)(bh * 2) * NCH + c) * CHSZ + (size_t)e0 * 128;
        int r = tid >> 4, gran = tid & 15;
        size_t goff = (size_t)r * 128 + ((gran ^ (r & 7)) * 8);
        #pragma unroll
        for (int kk = 0; kk < 2; ++kk) {
            const __bf16* sp = stb + (size_t)kk * NCH * CHSZ;
            #pragma unroll
            for (int it = 0; it < 4; ++it) {
                GLDS16(sp + goff + (size_t)it * 16 * 128,
                       (char*)STs[kk] + (it * 256 + w * 64) * 16);
            }
        }
    }

    if (tid < 128) {
        int s = tid & 63, kk = tid >> 6;
        size_t o = (size_t)(bh * 2 + kk) * T_DIM + c * LCH + s;
        rcumf[kk][s] = rcm[o];
        qscf[kk][s] = qscg[o];
    }

    bf16x8 vreg[2];
    #pragma unroll
    for (int it = 0; it < 2; ++it) {
        int f = tid + it * 256;
        int s = f >> 3, c8 = (f & 7) * 8;
        vreg[it] = *(const bf16x8*)(vg + (rowb + s) * C_DIM + h * D_H + e0 + c8);
    }

    const __bf16* qrow = qg + (rowb + w * 16 + lr) * C_DIM + h * D_H;
    bf16x8 aQ[4];
    #pragma unroll
    for (int kt = 0; kt < 4; ++kt)
        aQ[kt] = *(const bf16x8*)(qrow + kt * 32 + lg * 8);

    const __bf16* kbase = kg + rowb * C_DIM + h * D_H;
    bf16x8 bkreg[16];
    #pragma unroll
    for (int st = 0; st < 4; ++st)
        #pragma unroll
        for (int kt = 0; kt < 4; ++kt)
            bkreg[st * 4 + kt] = *(const bf16x8*)(kbase + (size_t)(st * 16 + lr) * C_DIM + kt * 32 + lg * 8);

    #pragma unroll
    for (int it = 0; it < 2; ++it) {
        int f = tid + it * 256;
        int s = f >> 3, c8 = (f & 7) * 8;
        #pragma unroll
        for (int j = 0; j < 8; ++j) {
            int el = c8 + j;
            VT[el * 64 + (s ^ SWE(el))] = vreg[it][j];
        }
    }

    f32x4 Praw[4];
    #pragma unroll
    for (int st = 0; st < 4; ++st) {
        f32x4 p = {};
        #pragma unroll
        for (int kt = 0; kt < 4; ++kt)
            p = __builtin_amdgcn_mfma_f32_16x16x32_bf16(aQ[kt], bkreg[st * 4 + kt], p, 0, 0, 0);
        Praw[st] = p;
    }

    asm volatile("s_waitcnt vmcnt(0)" ::: "memory");
    __syncthreads();

    f32x4 yA[4] = {};
    #pragma unroll
    for (int kk = 0; kk < 2; ++kk) {
        #pragma unroll
        for (int st = 0; st < 4; ++st) {
            #pragma unroll
            for (int r = 0; r < 4; ++r) {
                int tl = w * 16 + lg * 4 + r;
                int sc = st * 16 + lr;
                float pv = (sc <= tl) ? Praw[st][r] * rcumf[kk][sc] * qscf[kk][tl] : 0.f;
                Ps[tl * 72 + sc] = (__bf16)pv;
            }
        }
        bf16x8 aP[2];
        #pragma unroll
        for (int k2 = 0; k2 < 2; ++k2)
            aP[k2] = *(const bf16x8*)&Ps[(w * 16 + lr) * 72 + k2 * 32 + lg * 8];

        __builtin_amdgcn_s_setprio(1);
        #pragma unroll
        for (int et = 0; et < 4; ++et) {
            int el = et * 16 + lr;
            f32x4 ys = {};
            #pragma unroll
            for (int kt = 0; kt < 4; ++kt) {
                bf16x8 bs = *(const bf16x8*)((char*)STs[kk] + el * 256 + (((kt * 4 + lg) ^ (el & 7)) << 4));
                ys = __builtin_amdgcn_mfma_f32_16x16x32_bf16(aQ[kt], bs, ys, 0, 0, 0);
            }
            f32x4 yp = {};
            #pragma unroll
            for (int k2 = 0; k2 < 2; ++k2) {
                bf16x8 bv = *(const bf16x8*)&VT[el * 64 + ((k2 * 32 + lg * 8) ^ SWE(el))];
                yp = __builtin_amdgcn_mfma_f32_16x16x32_bf16(aP[k2], bv, yp, 0, 0, 0);
            }
            #pragma unroll
            for (int r = 0; r < 4; ++r)
                yA[et][r] += ys[r] * qscf[kk][w * 16 + lg * 4 + r] + yp[r];
        }
        __builtin_amdgcn_s_setprio(0);
    }
    #pragma unroll
    for (int et = 0; et < 4; ++et)
        #pragma unroll
        for (int r = 0; r < 4; ++r) {
            size_t row = rowb + w * 16 + lg * 4 + r;
            yg[row * C_DIM + h * D_H + e0 + et * 16 + lr] = (__bf16)yA[et][r];
        }
}

extern "C" void kernel_launch(void* const* d_in, const int* in_sizes, int n_in,
                              void* d_out, int out_size, void* d_ws, size_t ws_size,
                              hipStream_t stream) {
    const float* x    = (const float*)d_in[0];
    const int*   mask = (const int*)d_in[1];
    const float* Wq   = (const float*)d_in[2];
    const float* Wk   = (const float*)d_in[3];
    const float* Wv   = (const float*)d_in[4];
    const float* Wb   = (const float*)d_in[5];
    const float* bb   = (const float*)d_in[6];
    const float* Wm   = (const float*)d_in[7];
    const float* bm   = (const float*)d_in[8];
    const float* Wo   = (const float*)d_in[9];
    const float* bo   = (const float*)d_in[10];
    float* out = (float*)d_out;

    __bf16* q    = (__bf16*)d_ws;                 // MC (q,k,v contiguous)
    __bf16* k    = q + MC;
    __bf16* v    = k + MC;
    __bf16* xb   = v + MC;                        // reused as ysum
    __bf16* WT   = xb + MC;                       // WqT|WkT|WvT|WoT
    __bf16* BT   = WT + (size_t)4 * C_DIM * C_DIM;
    float* beta  = (float*)(BT + (size_t)64 * NCH * CHSZ);
    float* mixb  = beta + M_ROWS * 16;
    float* cumL  = mixb + M_ROWS * 16;
    float* wvm   = cumL + 64 * NCH;
    float* rcm   = wvm + (size_t)64 * T_DIM;
    float* qscg  = rcm + (size_t)64 * T_DIM;
    float2* rope = (float2*)(qscg + (size_t)64 * T_DIM);
    __bf16* WbmT = (__bf16*)(rope + T_DIM * 64);
    __bf16* ysum = xb;

    prep_all_k<<<dim3(5664), dim3(256), 0, stream>>>(
        x, xb, Wq, Wk, Wv, Wo, WT, rope, Wb, Wm, WbmT);
    betamix_mfma<<<dim3(M_ROWS / 32), dim3(256), 0, stream>>>(xb, WbmT, bb, bm, beta, mixb);
    decay_k<<<dim3(512), dim3(256), 0, stream>>>(beta, mixb, mask, wvm, rcm, qscg, cumL);

    const size_t CC = (size_t)C_DIM * C_DIM;
    gemm_qkv<<<dim3(1536), dim3(256), 0, stream>>>(xb, WT, q, rope);

    chunk_sum_k<<<dim3(NCH, 2, 32), dim3(256), 0, stream>>>(k, v, wvm, BT);
    chunk_scan_k<<<dim3(512), dim3(256), 0, stream>>>(BT, cumL);
    chunk_out_k<<<dim3(NCH, 2, 32), dim3(256), 0, stream>>>(q, k, v, BT, rcm, qscg, ysum);

    gemm_bt<<<dim3((M_ROWS / 128) * (C_DIM / 128)), dim3(256), 0, stream>>>(
        ysum, WT + 3 * CC, out, M_ROWS, C_DIM, C_DIM, bo);
}

// Round 20
// 214.506 us; speedup vs baseline: 1.1195x; 1.0061x over previous
//
#include <hip/hip_runtime.h>

typedef __attribute__((ext_vector_type(4))) float f32x4;
typedef __attribute__((ext_vector_type(8))) __bf16 bf16x8;

#define T_DIM 2048
#define B_DIM 4
#define C_DIM 1024
#define H_N 8
#define D_H 128
#define M_ROWS 8192   // B*T
#define MC ((size_t)M_ROWS * C_DIM)
#define LCH 64               // chunk length
#define NCH (T_DIM / LCH)    // 32 chunks
#define CHSZ (128 * 128)     // state tile elements
#define SWE(r) ((((r) ^ ((r) >> 3)) & 7) << 3)

#define GLDS16(g, l) __builtin_amdgcn_global_load_lds( \
    (const __attribute__((address_space(1))) void*)(g), \
    (__attribute__((address_space(3))) void*)(l), 16, 0, 0)

// ---------------- merged prep ----------------
__global__ __launch_bounds__(256) void prep_all_k(
    const float* __restrict__ x, __bf16* __restrict__ xb,
    const float* __restrict__ W0, const float* __restrict__ W1,
    const float* __restrict__ W2, const float* __restrict__ W3,
    __bf16* __restrict__ WT,
    float2* __restrict__ tab,
    const float* __restrict__ Wb, const float* __restrict__ Wm,
    __bf16* __restrict__ WbmT) {
    __shared__ float t[64][65];
    int bid = blockIdx.x;
    int tid = threadIdx.x;
    if (bid < 4096) {
        int i = bid * 256 + tid;
        f32x4 a = ((const f32x4*)x)[i * 2];
        f32x4 b = ((const f32x4*)x)[i * 2 + 1];
        bf16x8 o;
        o[0] = (__bf16)a.x; o[1] = (__bf16)a.y; o[2] = (__bf16)a.z; o[3] = (__bf16)a.w;
        o[4] = (__bf16)b.x; o[5] = (__bf16)b.y; o[6] = (__bf16)b.z; o[7] = (__bf16)b.w;
        ((bf16x8*)xb)[i] = o;
    } else if (bid < 5120) {
        int tt = bid - 4096;
        int wz = tt >> 8, rem = tt & 255;
        int r0 = (rem >> 4) * 64, c0 = (rem & 15) * 64;
        const float* W = wz == 0 ? W0 : wz == 1 ? W1 : wz == 2 ? W2 : W3;
        __bf16* o = WT + (size_t)wz * C_DIM * C_DIM;
        #pragma unroll
        for (int it = 0; it < 4; ++it) {
            int idx = it * 256 + tid;
            int r = idx >> 4, c4 = (idx & 15) * 4;
            f32x4 v = *(const f32x4*)(W + (size_t)(r0 + r) * C_DIM + c0 + c4);
            t[r][c4] = v.x; t[r][c4 + 1] = v.y; t[r][c4 + 2] = v.z; t[r][c4 + 3] = v.w;
        }
        __syncthreads();
        #pragma unroll
        for (int it = 0; it < 2; ++it) {
            int idx = it * 256 + tid;
            int n = idx >> 3, k8 = (idx & 7) * 8;
            bf16x8 ov;
            #pragma unroll
            for (int j = 0; j < 8; ++j) ov[j] = (__bf16)t[k8 + j][n];
            *(bf16x8*)(o + (size_t)(c0 + n) * C_DIM + r0 + k8) = ov;
        }
    } else {
        int sp = bid - 5120;
        if (sp < 512) {
            int idx = sp * 256 + tid;
            int tq = idx >> 6, i = idx & 63;
            float freq = expf(-(2.0f * (float)i / 128.0f) * 9.210340371976184f);
            float a = (float)tq * freq;
            tab[idx] = make_float2(cosf(a), sinf(a));
        } else {
            int n = sp - 512;               // 0..31
            int col = n & 15;
            const float* W = (n < 16) ? Wb : Wm;
            for (int k = tid; k < C_DIM; k += 256)
                WbmT[(size_t)n * C_DIM + k] = (__bf16)W[(size_t)k * 16 + col];
        }
    }
}

// ---------------- beta/mix via MFMA ----------------
__global__ __launch_bounds__(256) void betamix_mfma(
    const __bf16* __restrict__ xb, const __bf16* __restrict__ WbmT,
    const float* __restrict__ bb, const float* __restrict__ bm,
    float* __restrict__ beta, float* __restrict__ mix) {
    __shared__ __bf16 As[2][32 * 64];   // 2 x 4 KB

    int tid = threadIdx.x;
    int w = tid >> 6, lane = tid & 63;
    int lr = lane & 15, lg = lane >> 4;
    int ifr = w >> 1, j = w & 1;
    int rows0 = blockIdx.x * 32;

    int srow = tid >> 3;
    int sg = (tid & 7) ^ (srow & 7);
    size_t aoff = (size_t)(rows0 + srow) * C_DIM + sg * 8;
    int ldso = w * 64 * 16;

    f32x4 acc = {};
    const __bf16* Wrow = WbmT + (size_t)(j * 16 + lr) * C_DIM;

    GLDS16(xb + aoff, (char*)As[0] + ldso);
    asm volatile("s_waitcnt vmcnt(0)" ::: "memory");
    __syncthreads();

    for (int t = 0; t < 16; ++t) {
        int cur = t & 1;
        if (t < 15) GLDS16(xb + aoff + (t + 1) * 64, (char*)As[cur ^ 1] + ldso);
        #pragma unroll
        for (int ss = 0; ss < 2; ++ss) {
            int ar = ifr * 16 + lr;
            bf16x8 af = *(const bf16x8*)((char*)As[cur] + ar * 128 + (((ss * 4 + lg) ^ (ar & 7)) << 4));
            bf16x8 bf = *(const bf16x8*)(Wrow + t * 64 + ss * 32 + lg * 8);
            acc = __builtin_amdgcn_mfma_f32_16x16x32_bf16(af, bf, acc, 0, 0, 0);
        }
        asm volatile("s_waitcnt vmcnt(0)" ::: "memory");
        __syncthreads();
    }

    float bias = (j ? bm : bb)[lr];
    #pragma unroll
    for (int r = 0; r < 4; ++r) {
        int row = rows0 + ifr * 16 + lg * 4 + r;
        float v = acc[r] + bias;
        if (j == 0) {
            beta[(size_t)row * 16 + lr] = 1.f / (1.f + expf(-v));
        } else {
            float other = __shfl_xor(v, 1);
            float mx = fmaxf(v, other);
            float e = expf(v - mx), eo = expf(other - mx);
            mix[(size_t)row * 16 + lr] = e / (e + eo);
        }
    }
}

// ---------------- decay precompute ----------------
__global__ __launch_bounds__(256) void decay_k(
    const float* __restrict__ beta, const float* __restrict__ mixp,
    const int* __restrict__ mask,
    float* __restrict__ wvm, float* __restrict__ rcm,
    float* __restrict__ qsc, float* __restrict__ cumLg) {
    int gw = blockIdx.x * 4 + (threadIdx.x >> 6);
    int s = threadIdx.x & 63;
    int scan = gw >> 5, c = gw & 31;
    int b = scan >> 4, hh = scan & 15;
    size_t row = (size_t)b * T_DIM + c * LCH + s;
    int mk = mask[row];
    float mf = mk ? 1.f : 0.f;
    float bt = mk ? beta[row * 16 + hh] : 1.f;
    float mx = mk ? mixp[row * 16 + hh] : 0.f;
    float cum = bt;
    #pragma unroll
    for (int off = 1; off < 64; off <<= 1) {
        float p = __shfl(cum, (s >= off) ? s - off : 0);
        if (s >= off) cum *= p;
    }
    float cl = __shfl(cum, 63);
    size_t o = (size_t)scan * T_DIM + c * LCH + s;
    wvm[o] = mf * cl / cum;
    rcm[o] = mf / cum;
    qsc[o] = mf * mx * cum;
    if (s == 63) cumLg[scan * NCH + c] = cl;
}

// ---------------- fused q|k|v GEMM: single-buffered m97 structure --------
// best-measured qkv config (98.6 us). grid 1536 = 8 XCDs x {8 bm x 3 bn-groups}.
__global__ __launch_bounds__(256) void gemm_qkv(
    const __bf16* __restrict__ A, const __bf16* __restrict__ BT,
    __bf16* __restrict__ outq, const float2* __restrict__ rope_tab) {
    __shared__ __bf16 As[128 * 64];
    __shared__ __bf16 Bs[128 * 64];
    const int K = C_DIM;

    int tid = threadIdx.x;
    int xcd = blockIdx.x & 7, lid = blockIdx.x >> 3;
    int g = lid >> 6, u = lid & 63;
    int bm = xcd * 8 + (u >> 3), bn = g * 8 + (u & 7);
    int m_base = bm << 7, n_base = bn << 7;
    int w = tid >> 6, lane = tid & 63;
    int lr = lane & 15, lg = lane >> 4;
    int wm = (w >> 1) * 64, wn = (w & 1) * 64;

    size_t aoff[4], boff[4];
    int ldso[4];
    #pragma unroll
    for (int it = 0; it < 4; ++it) {
        int gi = it * 256 + tid;
        int row = gi >> 3;
        int gr = (gi & 7) ^ (row & 7);
        aoff[it] = (size_t)(m_base + row) * K + gr * 8;
        boff[it] = (size_t)(n_base + row) * K + gr * 8;
        ldso[it] = (it * 256 + w * 64) * 16;
    }

    f32x4 acc[4][4] = {};

    for (int k0 = 0; k0 < K; k0 += 64) {
        __syncthreads();
        #pragma unroll
        for (int it = 0; it < 4; ++it) {
            GLDS16(A + aoff[it] + k0, (char*)As + ldso[it]);
            GLDS16(BT + boff[it] + k0, (char*)Bs + ldso[it]);
        }
        __syncthreads();
        #pragma unroll
        for (int ss = 0; ss < 2; ++ss) {
            bf16x8 af[4], bfr[4];
            #pragma unroll
            for (int i = 0; i < 4; ++i) {
                int ar = wm + i * 16 + lr;
                af[i] = *(const bf16x8*)((char*)As + ar * 128 + (((ss * 4 + lg) ^ (ar & 7)) << 4));
                int br = wn + i * 16 + lr;
                bfr[i] = *(const bf16x8*)((char*)Bs + br * 128 + (((ss * 4 + lg) ^ (br & 7)) << 4));
            }
            #pragma unroll
            for (int i = 0; i < 4; ++i)
                #pragma unroll
                for (int j = 0; j < 4; ++j)
                    acc[i][j] = __builtin_amdgcn_mfma_f32_16x16x32_bf16(af[i], bfr[j], acc[i][j], 0, 0, 0);
        }
    }

    #pragma unroll
    for (int i = 0; i < 4; ++i) {
        #pragma unroll
        for (int j = 0; j < 4; ++j) {
            #pragma unroll
            for (int r = 0; r < 4; ++r) {
                int grow = m_base + wm + i * 16 + (lg << 2) + r;
                int gcol = n_base + wn + j * 16 + lr;
                float val = acc[i][j][r];
                int buf = gcol >> 10;
                int col = gcol & 1023;
                if (buf < 2) {
                    float partner = __shfl_xor(val, 1);
                    int t = grow & (T_DIM - 1);
                    int ii = (col & 127) >> 1;
                    float2 cs = rope_tab[t * 64 + ii];
                    val = (col & 1) ? (partner * cs.y + val * cs.x)
                                    : (val * cs.x - partner * cs.y);
                }
                outq[(size_t)buf * MC + (size_t)grow * C_DIM + col] = (__bf16)val;
            }
        }
    }
}

// ---------------- out GEMM: 128x128 2-phase dbuf --------------
__global__ __launch_bounds__(256) void gemm_bt(
    const __bf16* __restrict__ A, const __bf16* __restrict__ BT,
    float* __restrict__ Cp, int M, int N, int K,
    const float* __restrict__ bias) {
    __shared__ __bf16 As[2][128 * 64];
    __shared__ __bf16 Bs[2][128 * 64];

    int tid = threadIdx.x;
    int nTN = N >> 7;
    int cpx = gridDim.x >> 3;
    int bid = ((int)blockIdx.x & 7) * cpx + ((int)blockIdx.x >> 3);
    int bm = bid / nTN, bn = bid % nTN;
    int m_base = bm << 7, n_base = bn << 7;
    int w = tid >> 6, lane = tid & 63;
    int lr = lane & 15, lg = lane >> 4;
    int wm = (w >> 1) * 64, wn = (w & 1) * 64;

    size_t aoff[4], boff[4];
    int ldso[4];
    #pragma unroll
    for (int it = 0; it < 4; ++it) {
        int gi = it * 256 + tid;
        int row = gi >> 3;
        int g = (gi & 7) ^ (row & 7);
        aoff[it] = (size_t)(m_base + row) * K + g * 8;
        boff[it] = (size_t)(n_base + row) * K + g * 8;
        ldso[it] = (it * 256 + w * 64) * 16;
    }

#define STAGE_G(bufi, k0)                                                   \
    _Pragma("unroll")                                                       \
    for (int it = 0; it < 4; ++it) {                                        \
        GLDS16(A + aoff[it] + (k0), (char*)As[bufi] + ldso[it]);            \
        GLDS16(BT + boff[it] + (k0), (char*)Bs[bufi] + ldso[it]);           \
    }

    f32x4 acc[4][4] = {};

    STAGE_G(0, 0);
    asm volatile("s_waitcnt vmcnt(0)" ::: "memory");
    __syncthreads();

    int nt = K >> 6;
    for (int t = 0; t < nt; ++t) {
        int cur = t & 1;
        if (t + 1 < nt) STAGE_G(cur ^ 1, (t + 1) * 64);
        #pragma unroll
        for (int ss = 0; ss < 2; ++ss) {
            bf16x8 af[4], bfr[4];
            #pragma unroll
            for (int i = 0; i < 4; ++i) {
                int ar = wm + i * 16 + lr;
                af[i] = *(const bf16x8*)((char*)As[cur] + ar * 128 + (((ss * 4 + lg) ^ (ar & 7)) << 4));
                int br = wn + i * 16 + lr;
                bfr[i] = *(const bf16x8*)((char*)Bs[cur] + br * 128 + (((ss * 4 + lg) ^ (br & 7)) << 4));
            }
            #pragma unroll
            for (int i = 0; i < 4; ++i)
                #pragma unroll
                for (int j = 0; j < 4; ++j)
                    acc[i][j] = __builtin_amdgcn_mfma_f32_16x16x32_bf16(af[i], bfr[j], acc[i][j], 0, 0, 0);
        }
        asm volatile("s_waitcnt vmcnt(0)" ::: "memory");
        __syncthreads();
    }
#undef STAGE_G

    #pragma unroll
    for (int i = 0; i < 4; ++i) {
        #pragma unroll
        for (int j = 0; j < 4; ++j) {
            #pragma unroll
            for (int r = 0; r < 4; ++r) {
                int grow = m_base + wm + i * 16 + (lg << 2) + r;
                int gcol = n_base + wn + j * 16 + lr;
                Cp[(size_t)grow * N + gcol] = acc[i][j][r] + bias[gcol];
            }
        }
    }
}

// ============ chunk-parallel scan ============
__global__ __launch_bounds__(256) void chunk_sum_k(
    const __bf16* __restrict__ kg, const __bf16* __restrict__ vg,
    const float* __restrict__ wvm, __bf16* __restrict__ BT) {
    __shared__ __bf16 KT[128 * 64];
    __shared__ __bf16 VT[128 * 64];

    int tid = threadIdx.x;
    int c = blockIdx.x, kk = blockIdx.y, bh = blockIdx.z;
    int b = bh >> 3, h = bh & 7;
    int scan = bh * 2 + kk;
    size_t rowb = (size_t)b * T_DIM + c * LCH;
    size_t wb = (size_t)scan * T_DIM + c * LCH;

    #pragma unroll
    for (int it = 0; it < 4; ++it) {
        int f = tid + it * 256;
        int s = f >> 4, c8 = (f & 15) * 8;
        size_t g = (rowb + s) * C_DIM + h * D_H + c8;
        bf16x8 kv = *(const bf16x8*)(kg + g);
        bf16x8 vv = *(const bf16x8*)(vg + g);
        float ws_ = wvm[wb + s];
        #pragma unroll
        for (int j = 0; j < 8; ++j) {
            int d = c8 + j;
            KT[d * 64 + (s ^ SWE(d))] = (__bf16)(ws_ * (float)kv[j]);
            VT[d * 64 + (s ^ SWE(d))] = vv[j];
        }
    }
    __syncthreads();

    int w = tid >> 6, l = tid & 63;
    int lr = l & 15, lg = l >> 4;
    f32x4 acc[2][8] = {};
    #pragma unroll
    for (int kt = 0; kt < 2; ++kt) {
        int col = kt * 32 + lg * 8;
        bf16x8 aV[2], bK[8];
        #pragma unroll
        for (int et = 0; et < 2; ++et) {
            int e = w * 32 + et * 16 + lr;
            aV[et] = *(const bf16x8*)&VT[e * 64 + (col ^ SWE(e))];
        }
        #pragma unroll
        for (int dt = 0; dt < 8; ++dt) {
            int d = dt * 16 + lr;
            bK[dt] = *(const bf16x8*)&KT[d * 64 + (col ^ SWE(d))];
        }
        #pragma unroll
        for (int et = 0; et < 2; ++et)
            #pragma unroll
            for (int dt = 0; dt < 8; ++dt)
                acc[et][dt] = __builtin_amdgcn_mfma_f32_16x16x32_bf16(aV[et], bK[dt], acc[et][dt], 0, 0, 0);
    }

    __bf16* bout = BT + ((size_t)scan * NCH + c) * CHSZ;
    #pragma unroll
    for (int et = 0; et < 2; ++et)
        #pragma unroll
        for (int dt = 0; dt < 8; ++dt)
            #pragma unroll
            for (int r = 0; r < 4; ++r) {
                int e = w * 32 + et * 16 + lg * 4 + r;
                bout[e * 128 + dt * 16 + lr] = (__bf16)acc[et][dt][r];
            }
}

__global__ __launch_bounds__(256) void chunk_scan_k(
    __bf16* __restrict__ BT, const float* __restrict__ cumLg) {
    int bid = blockIdx.x;
    int scan = bid >> 3, part = bid & 7;
    int tid = threadIdx.x;
    int e = part * 16 + (tid >> 4);
    int d0 = (tid & 15) * 8;
    __bf16* base = BT + (size_t)scan * NCH * CHSZ + e * 128 + d0;
    const float* cl = cumLg + scan * NCH;
    float acc[8] = {};
    for (int c = 0; c < NCH; ++c) {
        bf16x8 bv = *(const bf16x8*)(base + (size_t)c * CHSZ);
        float g = cl[c];
        bf16x8 so;
        #pragma unroll
        for (int j = 0; j < 8; ++j) so[j] = (__bf16)acc[j];
        *(bf16x8*)(base + (size_t)c * CHSZ) = so;
        #pragma unroll
        for (int j = 0; j < 8; ++j) acc[j] = g * acc[j] + (float)bv[j];
    }
}

__global__ __launch_bounds__(256, 3) void chunk_out_k(
    const __bf16* __restrict__ qg, const __bf16* __restrict__ kg,
    const __bf16* __restrict__ vg, const __bf16* __restrict__ ST,
    const float* __restrict__ rcm, const float* __restrict__ qscg,
    __bf16* __restrict__ yg) {
    __shared__ __bf16 STs[2][64 * 128];  // 2 x 16 KB
    __shared__ __bf16 VT[64 * 64];       // 8 KB
    __shared__ __bf16 Ps[64 * 72];       // 9 KB
    __shared__ float rcumf[2][64], qscf[2][64];

    int tid = threadIdx.x;
    int c = blockIdx.x, eh = blockIdx.y, bh = blockIdx.z;
    int b = bh >> 3, h = bh & 7;
    int e0 = eh * 64;
    size_t rowb = (size_t)b * T_DIM + c * LCH;
    int w = tid >> 6, l = tid & 63;
    int lr = l & 15, lg = l >> 4;

    {
        const __bf16* stb = ST + ((size_t)(bh * 2) * NCH + c) * CHSZ + (size_t)e0 * 128;
        int r = tid >> 4, gran = tid & 15;
        size_t goff = (size_t)r * 128 + ((gran ^ (r & 7)) * 8);
        #pragma unroll
        for (int kk = 0; kk < 2; ++kk) {
            const __bf16* sp = stb + (size_t)kk * NCH * CHSZ;
            #pragma unroll
            for (int it = 0; it < 4; ++it) {
                GLDS16(sp + goff + (size_t)it * 16 * 128,
                       (char*)STs[kk] + (it * 256 + w * 64) * 16);
            }
        }
    }

    if (tid < 128) {
        int s = tid & 63, kk = tid >> 6;
        size_t o = (size_t)(bh * 2 + kk) * T_DIM + c * LCH + s;
        rcumf[kk][s] = rcm[o];
        qscf[kk][s] = qscg[o];
    }

    bf16x8 vreg[2];
    #pragma unroll
    for (int it = 0; it < 2; ++it) {
        int f = tid + it * 256;
        int s = f >> 3, c8 = (f & 7) * 8;
        vreg[it] = *(const bf16x8*)(vg + (rowb + s) * C_DIM + h * D_H + e0 + c8);
    }

    const __bf16* qrow = qg + (rowb + w * 16 + lr) * C_DIM + h * D_H;
    bf16x8 aQ[4];
    #pragma unroll
    for (int kt = 0; kt < 4; ++kt)
        aQ[kt] = *(const bf16x8*)(qrow + kt * 32 + lg * 8);

    const __bf16* kbase = kg + rowb * C_DIM + h * D_H;
    bf16x8 bkreg[16];
    #pragma unroll
    for (int st = 0; st < 4; ++st)
        #pragma unroll
        for (int kt = 0; kt < 4; ++kt)
            bkreg[st * 4 + kt] = *(const bf16x8*)(kbase + (size_t)(st * 16 + lr) * C_DIM + kt * 32 + lg * 8);

    #pragma unroll
    for (int it = 0; it < 2; ++it) {
        int f = tid + it * 256;
        int s = f >> 3, c8 = (f & 7) * 8;
        #pragma unroll
        for (int j = 0; j < 8; ++j) {
            int el = c8 + j;
            VT[el * 64 + (s ^ SWE(el))] = vreg[it][j];
        }
    }

    f32x4 Praw[4];
    #pragma unroll
    for (int st = 0; st < 4; ++st) {
        f32x4 p = {};
        #pragma unroll
        for (int kt = 0; kt < 4; ++kt)
            p = __builtin_amdgcn_mfma_f32_16x16x32_bf16(aQ[kt], bkreg[st * 4 + kt], p, 0, 0, 0);
        Praw[st] = p;
    }

    asm volatile("s_waitcnt vmcnt(0)" ::: "memory");
    __syncthreads();

    f32x4 yA[4] = {};
    #pragma unroll
    for (int kk = 0; kk < 2; ++kk) {
        #pragma unroll
        for (int st = 0; st < 4; ++st) {
            #pragma unroll
            for (int r = 0; r < 4; ++r) {
                int tl = w * 16 + lg * 4 + r;
                int sc = st * 16 + lr;
                float pv = (sc <= tl) ? Praw[st][r] * rcumf[kk][sc] * qscf[kk][tl] : 0.f;
                Ps[tl * 72 + sc] = (__bf16)pv;
            }
        }
        bf16x8 aP[2];
        #pragma unroll
        for (int k2 = 0; k2 < 2; ++k2)
            aP[k2] = *(const bf16x8*)&Ps[(w * 16 + lr) * 72 + k2 * 32 + lg * 8];

        __builtin_amdgcn_s_setprio(1);
        #pragma unroll
        for (int et = 0; et < 4; ++et) {
            int el = et * 16 + lr;
            f32x4 ys = {};
            #pragma unroll
            for (int kt = 0; kt < 4; ++kt) {
                bf16x8 bs = *(const bf16x8*)((char*)STs[kk] + el * 256 + (((kt * 4 + lg) ^ (el & 7)) << 4));
                ys = __builtin_amdgcn_mfma_f32_16x16x32_bf16(aQ[kt], bs, ys, 0, 0, 0);
            }
            f32x4 yp = {};
            #pragma unroll
            for (int k2 = 0; k2 < 2; ++k2) {
                bf16x8 bv = *(const bf16x8*)&VT[el * 64 + ((k2 * 32 + lg * 8) ^ SWE(el))];
                yp = __builtin_amdgcn_mfma_f32_16x16x32_bf16(aP[k2], bv, yp, 0, 0, 0);
            }
            #pragma unroll
            for (int r = 0; r < 4; ++r)
                yA[et][r] += ys[r] * qscf[kk][w * 16 + lg * 4 + r] + yp[r];
        }
        __builtin_amdgcn_s_setprio(0);
    }
    #pragma unroll
    for (int et = 0; et < 4; ++et)
        #pragma unroll
        for (int r = 0; r < 4; ++r) {
            size_t row = rowb + w * 16 + lg * 4 + r;
            yg[row * C_DIM + h * D_H + e0 + et * 16 + lr] = (__bf16)yA[et][r];
        }
}

extern "C" void kernel_launch(void* const* d_in, const int* in_sizes, int n_in,
                              void* d_out, int out_size, void* d_ws, size_t ws_size,
                              hipStream_t stream) {
    const float* x    = (const float*)d_in[0];
    const int*   mask = (const int*)d_in[1];
    const float* Wq   = (const float*)d_in[2];
    const float* Wk   = (const float*)d_in[3];
    const float* Wv   = (const float*)d_in[4];
    const float* Wb   = (const float*)d_in[5];
    const float* bb   = (const float*)d_in[6];
    const float* Wm   = (const float*)d_in[7];
    const float* bm   = (const float*)d_in[8];
    const float* Wo   = (const float*)d_in[9];
    const float* bo   = (const float*)d_in[10];
    float* out = (float*)d_out;

    __bf16* q    = (__bf16*)d_ws;                 // MC (q,k,v contiguous)
    __bf16* k    = q + MC;
    __bf16* v    = k + MC;
    __bf16* xb   = v + MC;                        // reused as ysum
    __bf16* WT   = xb + MC;                       // WqT|WkT|WvT|WoT
    __bf16* BT   = WT + (size_t)4 * C_DIM * C_DIM;
    float* beta  = (float*)(BT + (size_t)64 * NCH * CHSZ);
    float* mixb  = beta + M_ROWS * 16;
    float* cumL  = mixb + M_ROWS * 16;
    float* wvm   = cumL + 64 * NCH;
    float* rcm   = wvm + (size_t)64 * T_DIM;
    float* qscg  = rcm + (size_t)64 * T_DIM;
    float2* rope = (float2*)(qscg + (size_t)64 * T_DIM);
    __bf16* WbmT = (__bf16*)(rope + T_DIM * 64);
    __bf16* ysum = xb;

    prep_all_k<<<dim3(5664), dim3(256), 0, stream>>>(
        x, xb, Wq, Wk, Wv, Wo, WT, rope, Wb, Wm, WbmT);
    betamix_mfma<<<dim3(M_ROWS / 32), dim3(256), 0, stream>>>(xb, WbmT, bb, bm, beta, mixb);
    decay_k<<<dim3(512), dim3(256), 0, stream>>>(beta, mixb, mask, wvm, rcm, qscg, cumL);

    const size_t CC = (size_t)C_DIM * C_DIM;
    gemm_qkv<<<dim3(1536), dim3(256), 0, stream>>>(xb, WT, q, rope);

    chunk_sum_k<<<dim3(NCH, 2, 32), dim3(256), 0, stream>>>(k, v, wvm, BT);
    chunk_scan_k<<<dim3(512), dim3(256), 0, stream>>>(BT, cumL);
    chunk_out_k<<<dim3(NCH, 2, 32), dim3(256), 0, stream>>>(q, k, v, BT, rcm, qscg, ysum);

    gemm_bt<<<dim3((M_ROWS / 128) * (C_DIM / 128)), dim3(256), 0, stream>>>(
        ysum, WT + 3 * CC, out, M_ROWS, C_DIM, C_DIM, bo);
}